// Round 3
// baseline (7150.014 us; speedup 1.0000x reference)
//
#include <hip/hip_runtime.h>
#include <hip/hip_bf16.h>
#include <hip/hip_cooperative_groups.h>
#include <math.h>

namespace cg = cooperative_groups;

// CWVAE RSSM on MI355X, round 3: persistent cooperative scan kernel per level.
// All per-level weights (16.75 MB bf16 frag-packed) live in LDS across the
// whole T-step scan; grid.sync() between the 6 stages of each step.

#define FACT 6
#define NB 64
#define TT0 36
#define GBLK 179          // 171 generic (512 big tiles / 3) + 8 heads blocks
#define LDS_BYTES 120832  // 3*32K big + 4K h + 12K red + 6K tr

typedef __attribute__((ext_vector_type(8))) short bf16x8;
typedef __attribute__((ext_vector_type(4))) short bf16x4;
typedef __attribute__((ext_vector_type(4))) float f32x4;
typedef unsigned short u16;

#define MFMA(a, b, c) __builtin_amdgcn_mfma_f32_16x16x32_bf16(a, b, c, 0, 0, 0)

__device__ inline u16 f2bf(float x) {
    unsigned u = __float_as_uint(x);
    unsigned r = u + 0x7fffu + ((u >> 16) & 1u);  // RNE
    return (u16)(r >> 16);
}

// ---------------------------------------------------------------------------
// Mega-pack: all 9 weight kinds x 3 levels, fp32 [K,N] -> bf16 frag layout.
// frag(lane,e) = W[kt*32+(lane>>4)*8+e][nt*16+(lane&15)]
// Kinds: 0 W1S(128,1024) 1 W1C(1152,1024) 2 GWI(1024,3072) 3 GWH(1024,3072)
//        4 Q1D(1024,1024) 5 Q1O(1024,1024) 6 Q2(1024,1024) 7 WQM(1024,128) 8 WQS(1024,128)
__constant__ const int PFX[10] = {0, 256, 2560, 8704, 14848, 16896, 18944, 20992, 21248, 21504};
__constant__ const int KTS[9]  = {4, 36, 32, 32, 32, 32, 32, 32, 32};

__global__ __launch_bounds__(256) void k_pack_all(
    const float* __restrict__ w1, const float* __restrict__ gwi,
    const float* __restrict__ gwh, const float* __restrict__ q1,
    const float* __restrict__ q2, const float* __restrict__ wqm,
    const float* __restrict__ wqs, u16* __restrict__ dst) {
    int gid = blockIdx.x * 256 + threadIdx.x;
    int fu = gid >> 6, lane = gid & 63;
    int l = fu / 21504, f = fu % 21504;
    int kind = 0;
    while (f >= PFX[kind + 1]) ++kind;
    int local = f - PFX[kind];
    int KT = KTS[kind];
    int kt = local % KT, nt = local / KT;
    int k = kt * 32 + ((lane >> 4) << 3);
    int n = nt * 16 + (lane & 15);
    const float* src;
    int rw;
    switch (kind) {
        case 0: src = w1 + (size_t)l * 1310720 + (size_t)k * 1024 + n; rw = 1024; break;
        case 1: src = w1 + (size_t)l * 1310720 + (size_t)(128 + k) * 1024 + n; rw = 1024; break;
        case 2: src = gwi + (size_t)l * 3145728 + (size_t)k * 3072 + n; rw = 3072; break;
        case 3: src = gwh + (size_t)l * 3145728 + (size_t)k * 3072 + n; rw = 3072; break;
        case 4: src = q1 + (size_t)l * 2097152 + (size_t)k * 1024 + n; rw = 1024; break;
        case 5: src = q1 + (size_t)l * 2097152 + (size_t)(1024 + k) * 1024 + n; rw = 1024; break;
        case 6: src = q2 + (size_t)l * 1048576 + (size_t)k * 1024 + n; rw = 1024; break;
        case 7: src = wqm + (size_t)l * 131072 + (size_t)k * 128 + n; rw = 128; break;
        default: src = wqs + (size_t)l * 131072 + (size_t)k * 128 + n; rw = 128; break;
    }
    bf16x8 v;
#pragma unroll
    for (int e = 0; e < 8; ++e) v[e] = (short)f2bf(src[(size_t)e * rw]);
    reinterpret_cast<bf16x8*>(dst)[(size_t)fu * 64 + lane] = v;
}

// ---------------------------------------------------------------------------
// Precompute GEMM (LDS-staged A): out[M][1024] = A[M][ldA](fp32) @ P(bf16 frags)
// Grid (8, M/64), 512 thr. A staged fp32->bf16 into LDS in 256-col K-chunks.
__global__ __launch_bounds__(512) void k_gemm(
    const float* __restrict__ A, int ldA, int KTtot,
    const bf16x8* __restrict__ P, float* __restrict__ out) {
    __shared__ u16 ldsA[64 * 264];  // stride 264 (=256+8) kills bank conflicts
    int tid = threadIdx.x, lane = tid & 63, wave = tid >> 6;
    int nt = blockIdx.x * 8 + wave;
    int y = blockIdx.y;
    int K = KTtot * 32;
    int kfo = (lane >> 4) << 3;
    f32x4 acc[4] = {};
    for (int k0 = 0; k0 < K; k0 += 256) {
        int chunk = min(256, K - k0);
        int cf4 = chunk >> 2;
        for (int idx = tid; idx < 64 * cf4; idx += 512) {
            int row = idx / cf4, c4 = idx % cf4;
            float4 v = *(const float4*)(A + (size_t)(y * 64 + row) * ldA + k0 + c4 * 4);
            bf16x4 bv;
            bv[0] = (short)f2bf(v.x); bv[1] = (short)f2bf(v.y);
            bv[2] = (short)f2bf(v.z); bv[3] = (short)f2bf(v.w);
            *(bf16x4*)(&ldsA[row * 264 + c4 * 4]) = bv;
        }
        __syncthreads();
        int nkt = chunk >> 5;
        for (int ktl = 0; ktl < nkt; ++ktl) {
            int ktg = (k0 >> 5) + ktl;
#pragma unroll
            for (int m = 0; m < 4; ++m) {
                bf16x8 af = *(const bf16x8*)(&ldsA[(m * 16 + (lane & 15)) * 264 + ktl * 32 + kfo]);
                acc[m] = MFMA(af, P[((size_t)nt * KTtot + ktg) * 64 + lane], acc[m]);
            }
        }
        __syncthreads();
    }
    int colL = lane & 15;
#pragma unroll
    for (int m = 0; m < 4; ++m) {
        int row0 = m * 16 + ((lane >> 4) << 2);
#pragma unroll
        for (int j = 0; j < 4; ++j)
            out[(size_t)(y * 64 + row0 + j) * 1024 + nt * 16 + colL] = acc[m][j];
    }
}

// ---------------------------------------------------------------------------
// Persistent scan kernel (cooperative). 179 blocks x 512 threads.
// Big tile index B in [0,512): gi [0,192) gh [192,384) q1 [384,448) q2 [448,512)
// owner = B/3, slot = B%3. Heads blocks 171+i own qm_i (slot0), qs_i (slot1).
// h tiles (KT=4): block nt<64, separate 4KB LDS region.
struct ScanArgs {
    const u16* Pw;   // packed level base
    const float *b1, *gbi, *gbh, *qb1, *qb2, *bqm, *bqs;
    const float* cpre;  // null for top level
    const float* obs;
    const float* nq;
    float* outp;
    u16 *hB, *hq1B, *hq2B, *sampB;
    u16 *det16a, *det16b;
    float *detFa, *detFb;
    float *giF, *ghF;
    int T, Tup;
};

__global__ void __launch_bounds__(512, 2) k_scan(ScanArgs a) {
    cg::grid_group grid = cg::this_grid();
    extern __shared__ char smem[];
    u16* BIGu = (u16*)smem;                     // 3 x 32KB big tiles
    u16* HWu = (u16*)(smem + 98304);            // 4KB h tile
    f32x4* RED = (f32x4*)(smem + 102400);       // [3][4][64] f32x4
    u16* TRp = (u16*)(smem + 114688);           // [3][64][16] bf16

    int b = blockIdx.x, tid = threadIdx.x;
    int lane = tid & 63, wave = tid >> 6;
    int m = wave & 3, kh = wave >> 2;
    int kfo = (lane >> 4) << 3;
    int colL = lane & 15;
    int row0 = m * 16 + ((lane >> 4) << 2);
    int arow = m * 16 + (lane & 15);

    // ---- load this block's weight slice into LDS ----
    {
        const bf16x8* src = (const bf16x8*)a.Pw;
        bf16x8* dstB = (bf16x8*)BIGu;
        if (b < 171) {
#pragma unroll
            for (int s = 0; s < 3; ++s) {
                int B = 3 * b + s;
                if (B < 512) {
                    long fu;
                    if (B < 192) fu = 2560 + (long)B * 32;
                    else if (B < 384) fu = 8704 + (long)(B - 192) * 32;
                    else if (B < 448) fu = 14848 + (long)(B - 384) * 32;
                    else fu = 18944 + (long)(B - 448) * 32;
                    for (int i = 0; i < 4; ++i)
                        dstB[s * 2048 + tid + i * 512] = src[fu * 64 + tid + i * 512];
                }
            }
            if (b < 64 && tid < 256)  // h tile, kind0
                ((bf16x8*)HWu)[tid] = src[(long)b * 4 * 64 + tid];
        } else {
            int i = b - 171;
            long fm = 20992 + (long)i * 32, fs = 21248 + (long)i * 32;
            for (int it = 0; it < 4; ++it) {
                dstB[tid + it * 512] = src[fm * 64 + tid + it * 512];
                dstB[2048 + tid + it * 512] = src[fs * 64 + tid + it * 512];
            }
        }
        __syncthreads();
    }

    auto BIGF = [&](int s, int kt) -> bf16x8 {
        return *(const bf16x8*)(BIGu + s * 16384 + (kt * 64 + lane) * 8);
    };

    for (int t = 0; t < a.T; ++t) {
        int dn = t & 1, dold = dn ^ 1;
        u16* det16n = dn ? a.det16b : a.det16a;
        const u16* det16o = dn ? a.det16a : a.det16b;
        float* detFn = dn ? a.detFb : a.detFa;
        const float* detFo = dn ? a.detFa : a.detFb;

        // ================= stage 1: h = elu(samp@W1S + cpre + b1) ==========
        if (b < 64) {
            f32x4 acc = {};
            if (t > 0) {
                const u16* ar = a.sampB + (size_t)arow * 128 + kfo;
                for (int kt = kh * 2; kt < kh * 2 + 2; ++kt) {
                    bf16x8 av = *(const bf16x8*)(ar + kt * 32);
                    acc = MFMA(av, *(const bf16x8*)(HWu + (kt * 64 + lane) * 8), acc);
                }
            }
            if (kh) RED[m * 64 + lane] = acc;
            __syncthreads();
            if (!kh) {
                acc += RED[m * 64 + lane];
                int col = b * 16 + colL;
                float bv = a.b1[col];
#pragma unroll
                for (int j = 0; j < 4; ++j) {
                    int row = row0 + j;
                    float x = acc[j] + bv;
                    if (a.cpre)
                        x += a.cpre[(size_t)(t / FACT) * 1024 + (size_t)row * a.Tup * 1024 + col];
                    x = x > 0.f ? x : expm1f(x);
                    TRp[row * 16 + colL] = f2bf(x);
                }
            }
            __syncthreads();
            if (tid < 128) {
                int row = tid >> 1, seg = tid & 1;
                *(bf16x8*)(a.hB + (size_t)row * 1024 + b * 16 + seg * 8) =
                    *(const bf16x8*)(TRp + row * 16 + seg * 8);
            }
        }
        grid.sync();

        // ================= stage 2: gi = h@GWI ; gh = det_old@GWH ==========
        if (b < 128) {
            bool isgh = b >= 64;
            f32x4 acc[3] = {};
            if (!isgh || t > 0) {
                const u16* Ab = isgh ? det16o : a.hB;
                const u16* ar = Ab + (size_t)arow * 1024 + kfo;
                for (int kt = kh * 16; kt < kh * 16 + 16; ++kt) {
                    bf16x8 av = *(const bf16x8*)(ar + kt * 32);
                    acc[0] = MFMA(av, BIGF(0, kt), acc[0]);
                    acc[1] = MFMA(av, BIGF(1, kt), acc[1]);
                    acc[2] = MFMA(av, BIGF(2, kt), acc[2]);
                }
            }
            if (kh) {
#pragma unroll
                for (int s = 0; s < 3; ++s) RED[(s * 4 + m) * 64 + lane] = acc[s];
            }
            __syncthreads();
            if (!kh) {
                float* O = isgh ? a.ghF : a.giF;
                int base = b * 3 - (isgh ? 192 : 0);
#pragma unroll
                for (int s = 0; s < 3; ++s) {
                    f32x4 v = acc[s] + RED[(s * 4 + m) * 64 + lane];
                    int c = (base + s) * 16 + colL;
#pragma unroll
                    for (int j = 0; j < 4; ++j) O[(size_t)(row0 + j) * 3072 + c] = v[j];
                }
            }
        }
        grid.sync();

        // ================= stage 3: gates (elementwise) ====================
        {
            int i = b * 512 + tid;
            if (i < 65536) {
                int row = i >> 10, col = i & 1023;
                size_t o = (size_t)row * 3072 + col;
                float gir = a.giF[o], giz = a.giF[o + 1024], gin = a.giF[o + 2048];
                float ghr = a.ghF[o], ghz = a.ghF[o + 1024], ghn = a.ghF[o + 2048];
                float r = 1.f / (1.f + expf(-(gir + a.gbi[col] + ghr + a.gbh[col])));
                float z = 1.f / (1.f + expf(-(giz + a.gbi[1024 + col] + ghz + a.gbh[1024 + col])));
                float n = tanhf(gin + a.gbi[2048 + col] + r * (ghn + a.gbh[2048 + col]));
                float dov = t ? detFo[i] : 0.f;
                float dnv = (1.f - z) * n + z * dov;
                detFn[i] = dnv;
                det16n[i] = f2bf(dnv);
                a.outp[(size_t)row * a.T * 1152 + (size_t)t * 1152 + 128 + col] = dnv;
            }
        }
        grid.sync();

        // ================= stage 4: hq1 = elu(det_new@Q1D + obs + qb1) =====
        {
            unsigned mask = 0;
#pragma unroll
            for (int s = 0; s < 3; ++s) {
                int B = 3 * b + s;
                if (B >= 384 && B < 448) mask |= 1u << s;
            }
            if (mask) {
                f32x4 acc[3] = {};
                const u16* ar = det16n + (size_t)arow * 1024 + kfo;
                for (int kt = kh * 16; kt < kh * 16 + 16; ++kt) {
                    bf16x8 av = *(const bf16x8*)(ar + kt * 32);
                    if (mask & 1u) acc[0] = MFMA(av, BIGF(0, kt), acc[0]);
                    if (mask & 2u) acc[1] = MFMA(av, BIGF(1, kt), acc[1]);
                    if (mask & 4u) acc[2] = MFMA(av, BIGF(2, kt), acc[2]);
                }
                if (kh) {
#pragma unroll
                    for (int s = 0; s < 3; ++s)
                        if ((mask >> s) & 1u) RED[(s * 4 + m) * 64 + lane] = acc[s];
                }
                __syncthreads();
                if (!kh) {
#pragma unroll
                    for (int s = 0; s < 3; ++s)
                        if ((mask >> s) & 1u) {
                            f32x4 v = acc[s] + RED[(s * 4 + m) * 64 + lane];
                            int cb = 3 * b + s - 384;
                            int col = cb * 16 + colL;
#pragma unroll
                            for (int j = 0; j < 4; ++j) {
                                int row = row0 + j;
                                float x = v[j] + a.qb1[col] +
                                          a.obs[(size_t)t * 1024 + (size_t)row * a.T * 1024 + col];
                                x = x > 0.f ? x : expm1f(x);
                                TRp[s * 1024 + row * 16 + colL] = f2bf(x);
                            }
                        }
                }
                __syncthreads();
                if (tid < 384) {
                    int s = tid >> 7;
                    if ((mask >> s) & 1u) {
                        int r2 = tid & 127, row = r2 >> 1, seg = r2 & 1;
                        int cb = 3 * b + s - 384;
                        *(bf16x8*)(a.hq1B + (size_t)row * 1024 + cb * 16 + seg * 8) =
                            *(const bf16x8*)(TRp + s * 1024 + row * 16 + seg * 8);
                    }
                }
            }
        }
        grid.sync();

        // ================= stage 5: hq2 = elu(hq1@Q2 + qb2) ================
        {
            unsigned mask = 0;
#pragma unroll
            for (int s = 0; s < 3; ++s) {
                int B = 3 * b + s;
                if (B >= 448 && B < 512) mask |= 1u << s;
            }
            if (mask) {
                f32x4 acc[3] = {};
                const u16* ar = a.hq1B + (size_t)arow * 1024 + kfo;
                for (int kt = kh * 16; kt < kh * 16 + 16; ++kt) {
                    bf16x8 av = *(const bf16x8*)(ar + kt * 32);
                    if (mask & 1u) acc[0] = MFMA(av, BIGF(0, kt), acc[0]);
                    if (mask & 2u) acc[1] = MFMA(av, BIGF(1, kt), acc[1]);
                    if (mask & 4u) acc[2] = MFMA(av, BIGF(2, kt), acc[2]);
                }
                if (kh) {
#pragma unroll
                    for (int s = 0; s < 3; ++s)
                        if ((mask >> s) & 1u) RED[(s * 4 + m) * 64 + lane] = acc[s];
                }
                __syncthreads();
                if (!kh) {
#pragma unroll
                    for (int s = 0; s < 3; ++s)
                        if ((mask >> s) & 1u) {
                            f32x4 v = acc[s] + RED[(s * 4 + m) * 64 + lane];
                            int cb = 3 * b + s - 448;
                            int col = cb * 16 + colL;
#pragma unroll
                            for (int j = 0; j < 4; ++j) {
                                int row = row0 + j;
                                float x = v[j] + a.qb2[col];
                                x = x > 0.f ? x : expm1f(x);
                                TRp[s * 1024 + row * 16 + colL] = f2bf(x);
                            }
                        }
                }
                __syncthreads();
                if (tid < 384) {
                    int s = tid >> 7;
                    if ((mask >> s) & 1u) {
                        int r2 = tid & 127, row = r2 >> 1, seg = r2 & 1;
                        int cb = 3 * b + s - 448;
                        *(bf16x8*)(a.hq2B + (size_t)row * 1024 + cb * 16 + seg * 8) =
                            *(const bf16x8*)(TRp + s * 1024 + row * 16 + seg * 8);
                    }
                }
            }
        }
        grid.sync();

        // ================= stage 6: heads + sample =========================
        if (b >= 171) {
            int i = b - 171;
            f32x4 am = {}, as_ = {};
            const u16* ar = a.hq2B + (size_t)arow * 1024 + kfo;
            for (int kt = kh * 16; kt < kh * 16 + 16; ++kt) {
                bf16x8 av = *(const bf16x8*)(ar + kt * 32);
                am = MFMA(av, BIGF(0, kt), am);
                as_ = MFMA(av, BIGF(1, kt), as_);
            }
            if (kh) {
                RED[(0 * 4 + m) * 64 + lane] = am;
                RED[(1 * 4 + m) * 64 + lane] = as_;
            }
            __syncthreads();
            if (!kh) {
                am += RED[(0 * 4 + m) * 64 + lane];
                as_ += RED[(1 * 4 + m) * 64 + lane];
                int col = i * 16 + colL;
                float bmv = a.bqm[col], bsv = a.bqs[col];
#pragma unroll
                for (int j = 0; j < 4; ++j) {
                    int row = row0 + j;
                    float mean = am[j] + bmv;
                    float xs = as_[j] + bsv;
                    float sp = fmaxf(xs, 0.f) + log1pf(expf(-fabsf(xs)));
                    float q = mean + (sp + 1e-4f) *
                                         a.nq[(size_t)t * 128 + (size_t)row * a.T * 128 + col];
                    a.outp[(size_t)row * a.T * 1152 + (size_t)t * 1152 + col] = q;
                    TRp[row * 16 + colL] = f2bf(q);
                }
            }
            __syncthreads();
            if (tid < 128) {
                int row = tid >> 1, seg = tid & 1;
                *(bf16x8*)(a.sampB + (size_t)row * 128 + i * 16 + seg * 8) =
                    *(const bf16x8*)(TRp + row * 16 + seg * 8);
            }
        }
        grid.sync();
    }
}

// ---------------------------------------------------------------------------
extern "C" void kernel_launch(void* const* d_in, const int* in_sizes, int n_in,
                              void* d_out, int out_size, void* d_ws, size_t ws_size,
                              hipStream_t stream) {
    (void)n_in; (void)out_size; (void)ws_size;
    int ix[3], inq[3];
    if (in_sizes[1] == NB * TT0 * 128) {  // dict order
        ix[0] = 0; inq[0] = 2; ix[1] = 3; inq[1] = 5; ix[2] = 6; inq[2] = 8;
    } else {  // signature order
        ix[0] = 0; ix[1] = 1; ix[2] = 2; inq[0] = 6; inq[1] = 7; inq[2] = 8;
    }
    const float* x[3] = {(const float*)d_in[ix[0]], (const float*)d_in[ix[1]], (const float*)d_in[ix[2]]};
    const float* nqp[3] = {(const float*)d_in[inq[0]], (const float*)d_in[inq[1]], (const float*)d_in[inq[2]]};
    const float* w1w = (const float*)d_in[9];
    const float* b1  = (const float*)d_in[10];
    const float* gwi = (const float*)d_in[11];
    const float* gwh = (const float*)d_in[12];
    const float* gbi = (const float*)d_in[13];
    const float* gbh = (const float*)d_in[14];
    const float* q1w = (const float*)d_in[21];
    const float* qb1 = (const float*)d_in[22];
    const float* q2w = (const float*)d_in[23];
    const float* qb2 = (const float*)d_in[24];
    const float* wqm = (const float*)d_in[25];
    const float* bqm = (const float*)d_in[26];
    const float* wqs = (const float*)d_in[27];
    const float* bqs = (const float*)d_in[28];

    char* wsb = (char*)d_ws;
    size_t off = 0;
    auto alloc = [&](size_t bytes) {
        void* p = wsb + off;
        off = (off + bytes + 255) & ~(size_t)255;
        return p;
    };
    u16* wsW = (u16*)alloc((size_t)64512 * 1024);  // 66 MB packed weights
    const int Tarr[3] = {36, 6, 1};
    float* obs_pre[3];
    for (int l = 0; l < 3; ++l) obs_pre[l] = (float*)alloc((size_t)NB * Tarr[l] * 1024 * 4);
    float* c_pre[2];
    c_pre[0] = (float*)alloc((size_t)NB * 6 * 1024 * 4);
    c_pre[1] = (float*)alloc((size_t)NB * 1 * 1024 * 4);
    u16* hB   = (u16*)alloc((size_t)NB * 1024 * 2);
    u16* hq1B = (u16*)alloc((size_t)NB * 1024 * 2);
    u16* hq2B = (u16*)alloc((size_t)NB * 1024 * 2);
    u16* det16a = (u16*)alloc((size_t)NB * 1024 * 2);
    u16* det16b = (u16*)alloc((size_t)NB * 1024 * 2);
    float* detFa = (float*)alloc((size_t)NB * 1024 * 4);
    float* detFb = (float*)alloc((size_t)NB * 1024 * 4);
    float* giF = (float*)alloc((size_t)NB * 3072 * 4);
    float* ghF = (float*)alloc((size_t)NB * 3072 * 4);
    u16* sampB = (u16*)alloc((size_t)NB * 128 * 2);
    float* out1 = (float*)alloc((size_t)NB * 6 * 1152 * 4);
    float* out2 = (float*)alloc((size_t)NB * 1 * 1152 * 4);

    const int pf[9] = {0, 256, 2560, 8704, 14848, 16896, 18944, 20992, 21248};
    auto Pk = [&](int l, int kind) -> const bf16x8* {
        return (const bf16x8*)wsW + ((size_t)l * 21504 + pf[kind]) * 64;
    };

    // 1. pack all weights (one launch)
    k_pack_all<<<16128, 256, 0, stream>>>(w1w, gwi, gwh, q1w, q2w, wqm, wqs, wsW);

    // 2. obs precompute: obs_pre[l] = x[l] @ Q1O[l]
    for (int l = 0; l < 3; ++l)
        k_gemm<<<dim3(8, Tarr[l]), 512, 0, stream>>>(x[l], 1024, 32, Pk(l, 5), obs_pre[l]);

    float* outbuf[3] = {(float*)d_out, out1, out2};

    for (int l = 2; l >= 0; --l) {
        int Tup = (l == 2) ? 1 : Tarr[l + 1];
        if (l < 2)  // ctx precompute: c_pre[l] = outbuf[l+1] @ W1C[l]
            k_gemm<<<dim3(8, Tup), 512, 0, stream>>>(outbuf[l + 1], 1152, 36, Pk(l, 1), c_pre[l]);

        ScanArgs sa;
        sa.Pw = wsW + (size_t)l * 21504 * 512;
        sa.b1 = b1 + (size_t)l * 1024;
        sa.gbi = gbi + (size_t)l * 3072;
        sa.gbh = gbh + (size_t)l * 3072;
        sa.qb1 = qb1 + (size_t)l * 1024;
        sa.qb2 = qb2 + (size_t)l * 1024;
        sa.bqm = bqm + (size_t)l * 128;
        sa.bqs = bqs + (size_t)l * 128;
        sa.cpre = (l == 2) ? nullptr : c_pre[l];
        sa.obs = obs_pre[l];
        sa.nq = nqp[l];
        sa.outp = outbuf[l];
        sa.hB = hB; sa.hq1B = hq1B; sa.hq2B = hq2B; sa.sampB = sampB;
        sa.det16a = det16a; sa.det16b = det16b;
        sa.detFa = detFa; sa.detFb = detFb;
        sa.giF = giF; sa.ghF = ghF;
        sa.T = Tarr[l]; sa.Tup = Tup;
        void* kp[] = {&sa};
        hipLaunchCooperativeKernel((void*)k_scan, dim3(GBLK), dim3(512), kp, LDS_BYTES, stream);
    }
}

// Round 4
// 2614.857 us; speedup vs baseline: 2.7344x; 2.7344x over previous
//
#include <hip/hip_runtime.h>
#include <hip/hip_bf16.h>
#include <math.h>

// CWVAE RSSM on MI355X, round 4: persistent per-level kernel with custom
// flag barriers (agent-scope atomics through L3) instead of grid.sync().
// 128 blocks = 64 K-split pairs; weights LDS-resident; gates pair-local.

#define FACT 6
#define NB 64
#define TT0 36
#define NBLK 128
#define SMEM_BYTES 157696  // 96K WG + 52K XW + 4K RED + 2K TR

typedef __attribute__((ext_vector_type(8))) short bf16x8;
typedef __attribute__((ext_vector_type(4))) short bf16x4;
typedef __attribute__((ext_vector_type(4))) float f32x4;
typedef unsigned short u16;
typedef unsigned int u32;
typedef unsigned long long u64;

#define MFMA(a, b, c) __builtin_amdgcn_mfma_f32_16x16x32_bf16(a, b, c, 0, 0, 0)
#define SCOPE __HIP_MEMORY_SCOPE_AGENT

__device__ inline u16 f2bf(float x) {
    unsigned u = __float_as_uint(x);
    unsigned r = u + 0x7fffu + ((u >> 16) & 1u);  // RNE
    return (u16)(r >> 16);
}

__device__ inline u64 ald64(const u64* p) {
    return __hip_atomic_load((const u64*)p, __ATOMIC_RELAXED, SCOPE);
}
__device__ inline float aldf(const float* p) {
    return __hip_atomic_load(p, __ATOMIC_RELAXED, SCOPE);
}
__device__ inline void ast64(u64* p, u64 v) {
    __hip_atomic_store(p, v, __ATOMIC_RELAXED, SCOPE);
}
__device__ inline void astf(float* p, float v) {
    __hip_atomic_store(p, v, __ATOMIC_RELAXED, SCOPE);
}
__device__ inline void ast32(u32* p, u32 v) {
    __hip_atomic_store(p, v, __ATOMIC_RELAXED, SCOPE);
}
// 16B A-fragment via two 8B agent loads (L2-bypass, L3-coherent)
__device__ inline bf16x8 afrag(const u16* p) {
    union { u64 q[2]; bf16x8 v; } u;
    const u64* q = (const u64*)p;
    u.q[0] = ald64(q);
    u.q[1] = ald64(q + 1);
    return u.v;
}
__device__ inline void arrive(u32* c, int tid) {
    asm volatile("s_waitcnt vmcnt(0)" ::: "memory");
    __syncthreads();
    if (tid == 0) __hip_atomic_fetch_add(c, 1u, __ATOMIC_RELAXED, SCOPE);
}
__device__ inline void waitc(u32* c, u32 tgt, int tid) {
    if (tid == 0) {
        while (__hip_atomic_load(c, __ATOMIC_RELAXED, SCOPE) < tgt)
            __builtin_amdgcn_s_sleep(1);
    }
    __syncthreads();
}

// ---------------------------------------------------------------------------
// Mega-pack: fp32 [K,N] -> bf16 frag layout. frag(lane,e) =
// W[kt*32+(lane>>4)*8+e][nt*16+(lane&15)].
// Kinds 0-6 as before; f>=20992: QH = 16 tiles [wqm 8 cols | wqs 8 cols].
__constant__ const int PFX[8] = {0, 256, 2560, 8704, 14848, 16896, 18944, 20992};
__constant__ const int KTS[7] = {4, 36, 32, 32, 32, 32, 32};

__global__ __launch_bounds__(256) void k_pack_all(
    const float* __restrict__ w1, const float* __restrict__ gwi,
    const float* __restrict__ gwh, const float* __restrict__ q1,
    const float* __restrict__ q2, const float* __restrict__ wqm,
    const float* __restrict__ wqs, u16* __restrict__ dst) {
    int gid = blockIdx.x * 256 + threadIdx.x;
    int fu = gid >> 6, lane = gid & 63;
    int l = fu / 21504, f = fu % 21504;
    const float* src;
    int rw;
    if (f >= 20992) {  // QH interleaved heads tiles
        int fl = f - 20992;
        int nt = fl >> 5, kt = fl & 31;
        int k = kt * 32 + ((lane >> 4) << 3);
        int cl = lane & 15;
        const float* base = (cl < 8) ? wqm : wqs;
        src = base + (size_t)l * 131072 + (size_t)k * 128 + nt * 8 + (cl & 7);
        rw = 128;
    } else {
        int kind = 0;
        while (kind < 6 && f >= PFX[kind + 1]) ++kind;
        int local = f - PFX[kind];
        int KT = KTS[kind];
        int kt = local % KT, nt = local / KT;
        int k = kt * 32 + ((lane >> 4) << 3);
        int n = nt * 16 + (lane & 15);
        switch (kind) {
            case 0: src = w1 + (size_t)l * 1310720 + (size_t)k * 1024 + n; rw = 1024; break;
            case 1: src = w1 + (size_t)l * 1310720 + (size_t)(128 + k) * 1024 + n; rw = 1024; break;
            case 2: src = gwi + (size_t)l * 3145728 + (size_t)k * 3072 + n; rw = 3072; break;
            case 3: src = gwh + (size_t)l * 3145728 + (size_t)k * 3072 + n; rw = 3072; break;
            case 4: src = q1 + (size_t)l * 2097152 + (size_t)k * 1024 + n; rw = 1024; break;
            case 5: src = q1 + (size_t)l * 2097152 + (size_t)(1024 + k) * 1024 + n; rw = 1024; break;
            default: src = q2 + (size_t)l * 1048576 + (size_t)k * 1024 + n; rw = 1024; break;
        }
    }
    bf16x8 v;
#pragma unroll
    for (int e = 0; e < 8; ++e) v[e] = (short)f2bf(src[(size_t)e * rw]);
    reinterpret_cast<bf16x8*>(dst)[(size_t)fu * 64 + lane] = v;
}

// ---------------------------------------------------------------------------
// Precompute GEMM (LDS-staged A): out[M][1024] = A[M][ldA](fp32) @ P. Grid (8, M/64).
__global__ __launch_bounds__(512) void k_gemm(
    const float* __restrict__ A, int ldA, int KTtot,
    const bf16x8* __restrict__ P, float* __restrict__ out) {
    __shared__ u16 ldsA[64 * 264];
    int tid = threadIdx.x, lane = tid & 63, wave = tid >> 6;
    int nt = blockIdx.x * 8 + wave;
    int y = blockIdx.y;
    int K = KTtot * 32;
    int kfo = (lane >> 4) << 3;
    f32x4 acc[4] = {};
    for (int k0 = 0; k0 < K; k0 += 256) {
        int chunk = min(256, K - k0);
        int cf4 = chunk >> 2;
        for (int idx = tid; idx < 64 * cf4; idx += 512) {
            int row = idx / cf4, c4 = idx % cf4;
            float4 v = *(const float4*)(A + (size_t)(y * 64 + row) * ldA + k0 + c4 * 4);
            bf16x4 bv;
            bv[0] = (short)f2bf(v.x); bv[1] = (short)f2bf(v.y);
            bv[2] = (short)f2bf(v.z); bv[3] = (short)f2bf(v.w);
            *(bf16x4*)(&ldsA[row * 264 + c4 * 4]) = bv;
        }
        __syncthreads();
        int nkt = chunk >> 5;
        for (int ktl = 0; ktl < nkt; ++ktl) {
            int ktg = (k0 >> 5) + ktl;
#pragma unroll
            for (int m = 0; m < 4; ++m) {
                bf16x8 af = *(const bf16x8*)(&ldsA[(m * 16 + (lane & 15)) * 264 + ktl * 32 + kfo]);
                acc[m] = MFMA(af, P[((size_t)nt * KTtot + ktg) * 64 + lane], acc[m]);
            }
        }
        __syncthreads();
    }
    int colL = lane & 15;
#pragma unroll
    for (int m = 0; m < 4; ++m) {
        int row0 = m * 16 + ((lane >> 4) << 2);
#pragma unroll
        for (int j = 0; j < 4; ++j)
            out[(size_t)(y * 64 + row0 + j) * 1024 + nt * 16 + colL] = acc[m][j];
    }
}

// ---------------------------------------------------------------------------
// Persistent scan. 128 blocks x 512 thr. g = b>>1 (pair), half = b&1 (K-half).
// Roles: all blocks GRU (pair K-split); even: h + q1 (+heads if g<16);
// odd: q2 (+heads if g<16). Counters: C1..C5, P[64] pair, PH[16] heads-pair.
struct ScanArgs {
    const u16* Pw;
    const float *b1, *gbi, *gbh, *qb1, *qb2, *bqm, *bqs;
    const float *cpre, *obs, *nq;
    float* outp;
    u16 *h, *det16, *hq1, *hq2, *samp;
    float *detF, *part, *hpart;
    u32* cnt;
    int T, Tup;
};

__global__ void __launch_bounds__(512) k_scan(ScanArgs a) {
    extern __shared__ char smem[];
    u16* WG = (u16*)smem;                        // [6][16][64][8]  96K
    u16* XW = (u16*)(smem + 98304);              // role tiles      52K
    f32x4* RED = (f32x4*)(smem + 151552);        // [4][64]          4K
    u16* TR = (u16*)(smem + 155648);             // [64][16]         2K

    int tid = threadIdx.x, lane = tid & 63, wave = tid >> 6;
    int b = blockIdx.x, g = b >> 1, half = b & 1;
    int m = wave & 3;
    int kfo = (lane >> 4) << 3;
    int colL = lane & 15;
    int row0 = 16 * m + ((lane >> 4) << 2);
    int arow = 16 * m + (lane & 15);
    u32 *C1 = a.cnt, *C2 = a.cnt + 1, *C3 = a.cnt + 2, *C4 = a.cnt + 3, *C5 = a.cnt + 4;
    u32 *P = a.cnt + 8, *PH = a.cnt + 72;
    const int T = a.T;

    // ---- weight fill (plain loads; coherent via kernel boundary) ----
    {
        const bf16x8* src = (const bf16x8*)a.Pw;
        bf16x8* dst = (bf16x8*)WG;
        for (int i = tid; i < 6144; i += 512) {  // 6 tiles x 16 ktl x 64 lanes
            int s = i >> 10, rem = i & 1023, ktl = rem >> 6, ln = rem & 63;
            int gate = s % 3;
            long f = (s >= 3 ? 8704 : 2560) + ((long)(gate * 64 + g)) * 32 + half * 16 + ktl;
            dst[i] = src[f * 64 + ln];
        }
        if (half == 0) {
            bf16x8* dw = (bf16x8*)XW;  // W1S [4][64]
            for (int i = tid; i < 256; i += 512)
                dw[i] = src[((long)g * 4 + (i >> 6)) * 64 + (i & 63)];
            bf16x8* dq = (bf16x8*)(XW + 2048);  // Q1 [32][64] @4K
            for (int i = tid; i < 2048; i += 512)
                dq[i] = src[(14848 + (long)g * 32 + (i >> 6)) * 64 + (i & 63)];
            if (g < 16) {
                bf16x8* dh = (bf16x8*)(XW + 18432);  // QH [16][64] @36K
                for (int i = tid; i < 1024; i += 512)
                    dh[i] = src[(20992 + (long)g * 32 + half * 16 + (i >> 6)) * 64 + (i & 63)];
            }
        } else {
            bf16x8* dq = (bf16x8*)XW;  // Q2 [32][64]
            for (int i = tid; i < 2048; i += 512)
                dq[i] = src[(18944 + (long)g * 32 + (i >> 6)) * 64 + (i & 63)];
            if (g < 16) {
                bf16x8* dh = (bf16x8*)(XW + 16384);  // QH [16][64] @32K
                for (int i = tid; i < 1024; i += 512)
                    dh[i] = src[(20992 + (long)g * 32 + half * 16 + (i >> 6)) * 64 + (i & 63)];
            }
        }
        __syncthreads();
    }

    for (int t = 0; t < T; ++t) {
        int par = t & 1;
        u16* det16n = a.det16 + par * 65536;
        const u16* det16o = a.det16 + (par ^ 1) * 65536;
        u16* hq1n = a.hq1 + par * 65536;
        u16* hq2n = a.hq2 + par * 65536;

        // ===== stage 1: h = elu(samp@W1S + cpre + b1)  (even blocks) =====
        if (half == 0) {
            waitc(C5, 32u * t, tid);
            int kh = wave >> 2;
            f32x4 acc = {};
            if (t > 0) {
                const u16* ar = a.samp + (size_t)arow * 128 + kh * 64 + kfo;
#pragma unroll
                for (int kk = 0; kk < 2; ++kk) {
                    bf16x8 av = afrag(ar + kk * 32);
                    acc = MFMA(av, ((const bf16x8*)XW)[(kh * 2 + kk) * 64 + lane], acc);
                }
            }
            if (kh) RED[m * 64 + lane] = acc;
            __syncthreads();
            if (!kh) {
                acc += RED[m * 64 + lane];
                int col = g * 16 + colL;
                float bv = a.b1[col];
#pragma unroll
                for (int j = 0; j < 4; ++j) {
                    int row = row0 + j;
                    float x = acc[j] + bv;
                    if (a.cpre) x += a.cpre[((size_t)row * a.Tup + t / FACT) * 1024 + col];
                    x = x > 0.f ? x : expm1f(x);
                    TR[row * 16 + colL] = f2bf(x);
                }
            }
            __syncthreads();
            if (tid < 256) {
                int row = tid >> 2, seg = tid & 3;
                ast64((u64*)(a.h + (size_t)row * 1024 + g * 16) + seg,
                      ((const u64*)(TR + row * 16))[seg]);
            }
            arrive(C1, tid);
        }

        // ===== stage 2: GRU (all blocks; pair K-split) =====
        waitc(C1, 64u * (t + 1), tid);
        {
            int grp = wave >> 2;  // 0: gi (A=h), 1: gh (A=det_old)
            f32x4 ac0 = {}, ac1 = {}, ac2 = {};
            if (grp == 0 || t > 0) {
                const u16* Ab = grp ? det16o : a.h;
                const u16* ar = Ab + (size_t)arow * 1024 + half * 512 + kfo;
                const bf16x8* wt = (const bf16x8*)WG + grp * 3072;
                for (int kt = 0; kt < 16; ++kt) {
                    bf16x8 av = afrag(ar + kt * 32);
                    ac0 = MFMA(av, wt[kt * 64 + lane], ac0);
                    ac1 = MFMA(av, wt[(16 + kt) * 64 + lane], ac1);
                    ac2 = MFMA(av, wt[(32 + kt) * 64 + lane], ac2);
                }
            }
            float* pb = a.part + ((size_t)((half * 2 + grp) * 64 + g)) * 3072;
#pragma unroll
            for (int j = 0; j < 4; ++j) {
                float* pr = pb + (size_t)(row0 + j) * 48 + colL;
                astf(pr, ac0[j]);
                astf(pr + 16, ac1[j]);
                astf(pr + 32, ac2[j]);
            }
        }
        arrive(P + g, tid);
        waitc(P + g, 2u * (t + 1), tid);
        // gates: rows [half*32, +32), local cols [0,16)
        if (tid < 256) {
            int rl = tid >> 3, cp = tid & 7;
            int row = half * 32 + rl;
            const float* p00 = a.part + ((size_t)(0 * 64 + g)) * 3072 + (size_t)row * 48;
            const float* p01 = a.part + ((size_t)(1 * 64 + g)) * 3072 + (size_t)row * 48;
            const float* p10 = a.part + ((size_t)(2 * 64 + g)) * 3072 + (size_t)row * 48;
            const float* p11 = a.part + ((size_t)(3 * 64 + g)) * 3072 + (size_t)row * 48;
            u32 pk = 0;
#pragma unroll
            for (int i2 = 0; i2 < 2; ++i2) {
                int c = cp * 2 + i2;
                int col = g * 16 + c;
                float gir = aldf(p00 + c) + aldf(p10 + c);
                float giz = aldf(p00 + 16 + c) + aldf(p10 + 16 + c);
                float gin = aldf(p00 + 32 + c) + aldf(p10 + 32 + c);
                float ghr = aldf(p01 + c) + aldf(p11 + c);
                float ghz = aldf(p01 + 16 + c) + aldf(p11 + 16 + c);
                float ghn = aldf(p01 + 32 + c) + aldf(p11 + 32 + c);
                float r = 1.f / (1.f + expf(-(gir + a.gbi[col] + ghr + a.gbh[col])));
                float z = 1.f / (1.f + expf(-(giz + a.gbi[1024 + col] + ghz + a.gbh[1024 + col])));
                float n = tanhf(gin + a.gbi[2048 + col] + r * (ghn + a.gbh[2048 + col]));
                float dold = t ? a.detF[(size_t)row * 1024 + col] : 0.f;
                float dn = (1.f - z) * n + z * dold;
                a.detF[(size_t)row * 1024 + col] = dn;
                a.outp[((size_t)row * T + t) * 1152 + 128 + col] = dn;
                pk |= ((u32)f2bf(dn)) << (16 * i2);
            }
            ast32((u32*)(det16n + (size_t)row * 1024 + g * 16 + cp * 2), pk);
        }
        arrive(C2, tid);

        // ===== stage 3/4: q1 (even) | q2 (odd) =====
        if (half == 0) {
            waitc(C2, 128u * (t + 1), tid);
            int kh = wave >> 2;
            f32x4 acc = {};
            const u16* ar = det16n + (size_t)arow * 1024 + kh * 512 + kfo;
            const bf16x8* wq = (const bf16x8*)(XW + 2048);
            for (int kt = 0; kt < 16; ++kt) {
                bf16x8 av = afrag(ar + kt * 32);
                acc = MFMA(av, wq[(kh * 16 + kt) * 64 + lane], acc);
            }
            if (kh) RED[m * 64 + lane] = acc;
            __syncthreads();
            if (!kh) {
                acc += RED[m * 64 + lane];
                int col = g * 16 + colL;
                float bv = a.qb1[col];
#pragma unroll
                for (int j = 0; j < 4; ++j) {
                    int row = row0 + j;
                    float x = acc[j] + bv + a.obs[((size_t)row * T + t) * 1024 + col];
                    x = x > 0.f ? x : expm1f(x);
                    TR[row * 16 + colL] = f2bf(x);
                }
            }
            __syncthreads();
            if (tid < 256) {
                int row = tid >> 2, seg = tid & 3;
                ast64((u64*)(hq1n + (size_t)row * 1024 + g * 16) + seg,
                      ((const u64*)(TR + row * 16))[seg]);
            }
            arrive(C3, tid);
        } else {
            waitc(C3, 64u * (t + 1), tid);
            int kh = wave >> 2;
            f32x4 acc = {};
            const u16* ar = hq1n + (size_t)arow * 1024 + kh * 512 + kfo;
            const bf16x8* wq = (const bf16x8*)XW;
            for (int kt = 0; kt < 16; ++kt) {
                bf16x8 av = afrag(ar + kt * 32);
                acc = MFMA(av, wq[(kh * 16 + kt) * 64 + lane], acc);
            }
            if (kh) RED[m * 64 + lane] = acc;
            __syncthreads();
            if (!kh) {
                acc += RED[m * 64 + lane];
                int col = g * 16 + colL;
                float bv = a.qb2[col];
#pragma unroll
                for (int j = 0; j < 4; ++j) {
                    int row = row0 + j;
                    float x = acc[j] + bv;
                    x = x > 0.f ? x : expm1f(x);
                    TR[row * 16 + colL] = f2bf(x);
                }
            }
            __syncthreads();
            if (tid < 256) {
                int row = tid >> 2, seg = tid & 3;
                ast64((u64*)(hq2n + (size_t)row * 1024 + g * 16) + seg,
                      ((const u64*)(TR + row * 16))[seg]);
            }
            arrive(C4, tid);
        }

        // ===== stage 5: heads (pairs g<16, both halves, K-split) =====
        if (g < 16) {
            waitc(C4, 64u * (t + 1), tid);
            int kq = wave >> 2;
            f32x4 acc = {};
            const u16* ar = hq2n + (size_t)arow * 1024 + half * 512 + kq * 256 + kfo;
            const bf16x8* wh = (const bf16x8*)(XW + (half ? 16384 : 18432));
            for (int kt = 0; kt < 8; ++kt) {
                bf16x8 av = afrag(ar + kt * 32);
                acc = MFMA(av, wh[(kq * 8 + kt) * 64 + lane], acc);
            }
            if (kq) RED[m * 64 + lane] = acc;
            __syncthreads();
            if (!kq) {
                acc += RED[m * 64 + lane];
                float* hp = a.hpart + ((size_t)(half * 16 + g)) * 1024;
#pragma unroll
                for (int j = 0; j < 4; ++j) astf(hp + (size_t)(row0 + j) * 16 + colL, acc[j]);
            }
            arrive(PH + g, tid);
            waitc(PH + g, 2u * (t + 1), tid);
            if (tid < 128) {
                int rl = tid >> 2, cp = tid & 3;
                int row = half * 32 + rl;
                const float* h0 = a.hpart + ((size_t)(0 * 16 + g)) * 1024 + (size_t)row * 16;
                const float* h1 = a.hpart + ((size_t)(1 * 16 + g)) * 1024 + (size_t)row * 16;
                u32 pk = 0;
#pragma unroll
                for (int i2 = 0; i2 < 2; ++i2) {
                    int c = cp * 2 + i2;
                    float mean = aldf(h0 + c) + aldf(h1 + c) + a.bqm[g * 8 + c];
                    float xs = aldf(h0 + 8 + c) + aldf(h1 + 8 + c) + a.bqs[g * 8 + c];
                    float sp = fmaxf(xs, 0.f) + log1pf(expf(-fabsf(xs)));
                    float q = mean + (sp + 1e-4f) * a.nq[((size_t)row * T + t) * 128 + g * 8 + c];
                    a.outp[((size_t)row * T + t) * 1152 + g * 8 + c] = q;
                    pk |= ((u32)f2bf(q)) << (16 * i2);
                }
                ast32((u32*)(a.samp + (size_t)row * 128 + g * 8 + cp * 2), pk);
            }
            arrive(C5, tid);
        }
    }
}

// ---------------------------------------------------------------------------
extern "C" void kernel_launch(void* const* d_in, const int* in_sizes, int n_in,
                              void* d_out, int out_size, void* d_ws, size_t ws_size,
                              hipStream_t stream) {
    (void)n_in; (void)out_size; (void)ws_size;
    int ix[3], inq[3];
    if (in_sizes[1] == NB * TT0 * 128) {  // dict order
        ix[0] = 0; inq[0] = 2; ix[1] = 3; inq[1] = 5; ix[2] = 6; inq[2] = 8;
    } else {  // signature order
        ix[0] = 0; ix[1] = 1; ix[2] = 2; inq[0] = 6; inq[1] = 7; inq[2] = 8;
    }
    const float* x[3] = {(const float*)d_in[ix[0]], (const float*)d_in[ix[1]], (const float*)d_in[ix[2]]};
    const float* nqp[3] = {(const float*)d_in[inq[0]], (const float*)d_in[inq[1]], (const float*)d_in[inq[2]]};
    const float* w1w = (const float*)d_in[9];
    const float* b1  = (const float*)d_in[10];
    const float* gwi = (const float*)d_in[11];
    const float* gwh = (const float*)d_in[12];
    const float* gbi = (const float*)d_in[13];
    const float* gbh = (const float*)d_in[14];
    const float* q1w = (const float*)d_in[21];
    const float* qb1 = (const float*)d_in[22];
    const float* q2w = (const float*)d_in[23];
    const float* qb2 = (const float*)d_in[24];
    const float* wqm = (const float*)d_in[25];
    const float* bqm = (const float*)d_in[26];
    const float* wqs = (const float*)d_in[27];
    const float* bqs = (const float*)d_in[28];

    char* wsb = (char*)d_ws;
    size_t off = 0;
    auto alloc = [&](size_t bytes) {
        void* p = wsb + off;
        off = (off + bytes + 255) & ~(size_t)255;
        return p;
    };
    u16* wsW = (u16*)alloc((size_t)64512 * 1024);
    const int Tarr[3] = {36, 6, 1};
    float* obs_pre[3];
    for (int l = 0; l < 3; ++l) obs_pre[l] = (float*)alloc((size_t)NB * Tarr[l] * 1024 * 4);
    float* c_pre[2];
    c_pre[0] = (float*)alloc((size_t)NB * 6 * 1024 * 4);
    c_pre[1] = (float*)alloc((size_t)NB * 1 * 1024 * 4);
    u16* hB    = (u16*)alloc((size_t)65536 * 2);
    u16* det16 = (u16*)alloc((size_t)2 * 65536 * 2);
    u16* hq1B  = (u16*)alloc((size_t)2 * 65536 * 2);
    u16* hq2B  = (u16*)alloc((size_t)2 * 65536 * 2);
    u16* sampB = (u16*)alloc((size_t)8192 * 2);
    float* detF  = (float*)alloc((size_t)65536 * 4);
    float* partB = (float*)alloc((size_t)786432 * 4);
    float* hpart = (float*)alloc((size_t)32768 * 4);
    float* out1 = (float*)alloc((size_t)NB * 6 * 1152 * 4);
    float* out2 = (float*)alloc((size_t)NB * 1 * 1152 * 4);
    u32* cnt = (u32*)alloc(3 * 128 * 4);

    hipMemsetAsync(cnt, 0, 3 * 128 * 4, stream);

    const int pf[6] = {0, 256, 2560, 8704, 14848, 18944};
    (void)pf;
    auto Pk = [&](int l, int kind_off) -> const bf16x8* {
        return (const bf16x8*)wsW + ((size_t)l * 21504 + kind_off) * 64;
    };

    k_pack_all<<<16128, 256, 0, stream>>>(w1w, gwi, gwh, q1w, q2w, wqm, wqs, wsW);
    for (int l = 0; l < 3; ++l)
        k_gemm<<<dim3(8, Tarr[l]), 512, 0, stream>>>(x[l], 1024, 32, Pk(l, 16896), obs_pre[l]);

    float* outbuf[3] = {(float*)d_out, out1, out2};

    for (int l = 2; l >= 0; --l) {
        int Tup = (l == 2) ? 1 : Tarr[l + 1];
        if (l < 2)
            k_gemm<<<dim3(8, Tup), 512, 0, stream>>>(outbuf[l + 1], 1152, 36, Pk(l, 256), c_pre[l]);

        ScanArgs sa;
        sa.Pw = wsW + (size_t)l * 21504 * 512;
        sa.b1 = b1 + (size_t)l * 1024;
        sa.gbi = gbi + (size_t)l * 3072;
        sa.gbh = gbh + (size_t)l * 3072;
        sa.qb1 = qb1 + (size_t)l * 1024;
        sa.qb2 = qb2 + (size_t)l * 1024;
        sa.bqm = bqm + (size_t)l * 128;
        sa.bqs = bqs + (size_t)l * 128;
        sa.cpre = (l == 2) ? nullptr : c_pre[l];
        sa.obs = obs_pre[l];
        sa.nq = nqp[l];
        sa.outp = outbuf[l];
        sa.h = hB; sa.det16 = det16; sa.hq1 = hq1B; sa.hq2 = hq2B; sa.samp = sampB;
        sa.detF = detF; sa.part = partB; sa.hpart = hpart;
        sa.cnt = cnt + (size_t)(2 - l) * 128;  // fresh counters per level
        sa.T = Tarr[l]; sa.Tup = Tup;
        void* kp[] = {&sa};
        hipLaunchCooperativeKernel((void*)k_scan, dim3(NBLK), dim3(512), kp, SMEM_BYTES, stream);
    }
}